// Round 1
// baseline (377.817 us; speedup 1.0000x reference)
//
#include <hip/hip_runtime.h>
#include <hip/hip_bf16.h>

typedef __attribute__((ext_vector_type(8))) short bf16x8;
typedef __attribute__((ext_vector_type(4))) float f32x4;
typedef __attribute__((ext_vector_type(4))) int int4v;

#define BATCH 8
#define LEN 4096
#define DIN 1024
#define DST 512
#define KHALF 256
#define DOUT 1024
#define NCHUNK 64
#define CHUNK 64

static __device__ __forceinline__ ushort f2bf(float f) {
    // round-to-nearest-even f32 -> bf16
    uint x = __float_as_uint(f);
    uint r = (x + 0x7fffu + ((x >> 16) & 1u)) >> 16;
    return (ushort)r;
}

// ---------------- rmsnorm: u (32768 x 1024) f32 -> un bf16 ----------------
__global__ __launch_bounds__(256)
void rmsnorm_kernel(const float* __restrict__ u, const float* __restrict__ w,
                    ushort* __restrict__ un)
{
    const int row = blockIdx.x;
    const int t = threadIdx.x;
    const float4 v = ((const float4*)(u + (size_t)row * DIN))[t];
    float ss = v.x*v.x + v.y*v.y + v.z*v.z + v.w*v.w;
    #pragma unroll
    for (int m = 32; m >= 1; m >>= 1) ss += __shfl_xor(ss, m, 64);
    __shared__ float partial[4];
    if ((t & 63) == 0) partial[t >> 6] = ss;
    __syncthreads();
    const float total = partial[0] + partial[1] + partial[2] + partial[3];
    const float scale = rsqrtf(total * (1.0f / DIN) + 1e-6f);
    const float4 wv = ((const float4*)w)[t];
    ushort4 o;
    o.x = f2bf(v.x * scale * wv.x);
    o.y = f2bf(v.y * scale * wv.y);
    o.z = f2bf(v.z * scale * wv.z);
    o.w = f2bf(v.w * scale * wv.w);
    ((ushort4*)(un + (size_t)row * DIN))[t] = o;
}

// ---------------- transpose + cast to bf16: dst[c][r] = src[r][c] ----------------
__global__ __launch_bounds__(256)
void transpose_bf16_kernel(const float* __restrict__ src, ushort* __restrict__ dst,
                           int R, int C)
{
    const int id = blockIdx.x * 256 + threadIdx.x;
    if (id >= R * C) return;
    const int r = id / C, c = id % C;
    dst[(size_t)c * R + r] = f2bf(src[id]);
}

// ---------------- bf16 MFMA GEMM: A[M][K] @ B (given as Bt[N][K]) -> C[M][N] f32 ----------------
// 128x128 tile, 4 waves (2x2), each wave 64x64 via 4x4 frags of 16x16x32 MFMA.
#define BM 128
#define BN 128
#define BK 64
__global__ __launch_bounds__(256, 2)
void gemm_bt_kernel(const ushort* __restrict__ A, const ushort* __restrict__ Bt,
                    float* __restrict__ C, int M, int N, int K)
{
    __shared__ ushort sA[BM * BK];
    __shared__ ushort sB[BN * BK];
    const int tid = threadIdx.x;
    const int lane = tid & 63;
    const int wave = tid >> 6;
    const int wr = wave >> 1, wc = wave & 1;
    const int m0 = blockIdx.x * BM, n0 = blockIdx.y * BN;

    // staging: thread covers row sr = tid>>1 (0..127), half sh = (tid&1)*32 elems
    const int sr = tid >> 1;
    const int sh = (tid & 1) * 32;
    const ushort* gA = A + (size_t)(m0 + sr) * K + sh;
    const ushort* gB = Bt + (size_t)(n0 + sr) * K + sh;

    f32x4 acc[4][4] = {};

    const int nkt = K / BK;
    for (int kt = 0; kt < nkt; ++kt) {
        int4v ra[4], rb[4];
        const ushort* pa = gA + kt * BK;
        const ushort* pb = gB + kt * BK;
        #pragma unroll
        for (int j = 0; j < 4; ++j) {
            ra[j] = *(const int4v*)(pa + j * 8);
            rb[j] = *(const int4v*)(pb + j * 8);
        }
        __syncthreads();   // previous tile's compute done
        #pragma unroll
        for (int j = 0; j < 4; ++j) {
            const int off = sr * 128 + ((sh * 2 + j * 16) ^ ((sr & 7) << 4));
            *(int4v*)((char*)sA + off) = ra[j];
            *(int4v*)((char*)sB + off) = rb[j];
        }
        __syncthreads();
        #pragma unroll
        for (int kk = 0; kk < 2; ++kk) {
            bf16x8 af[4], bfr[4];
            #pragma unroll
            for (int i = 0; i < 4; ++i) {
                const int arow = wr * 64 + i * 16 + (lane & 15);
                const int aoff = arow * 128 + ((kk * 64 + (lane >> 4) * 16) ^ ((arow & 7) << 4));
                af[i] = *(const bf16x8*)((const char*)sA + aoff);
                const int brow = wc * 64 + i * 16 + (lane & 15);
                const int boff = brow * 128 + ((kk * 64 + (lane >> 4) * 16) ^ ((brow & 7) << 4));
                bfr[i] = *(const bf16x8*)((const char*)sB + boff);
            }
            #pragma unroll
            for (int i = 0; i < 4; ++i)
                #pragma unroll
                for (int j = 0; j < 4; ++j)
                    acc[i][j] = __builtin_amdgcn_mfma_f32_16x16x32_bf16(af[i], bfr[j], acc[i][j], 0, 0, 0);
        }
    }
    // epilogue: C[(lane>>4)*4 + r][lane&15] per frag (m89-verified layout)
    #pragma unroll
    for (int i = 0; i < 4; ++i) {
        #pragma unroll
        for (int j = 0; j < 4; ++j) {
            const int row = m0 + wr * 64 + i * 16 + (lane >> 4) * 4;
            const int col = n0 + wc * 64 + j * 16 + (lane & 15);
            float* cp = C + (size_t)row * N + col;
            #pragma unroll
            for (int r = 0; r < 4; ++r)
                cp[(size_t)r * N] = acc[i][j][r];
        }
    }
}

// ---------------- scan phase A: per-chunk local finals (zero carry-in) ----------------
// L layout: [b][chunk][k] float2
__global__ __launch_bounds__(256)
void scan_local_kernel(const float* __restrict__ uB, const float* __restrict__ A,
                       float* __restrict__ L)
{
    const int c = blockIdx.x, b = blockIdx.y, k = threadIdx.x;
    const float a00 = A[4*k+0], a01 = A[4*k+1], a10 = A[4*k+2], a11 = A[4*k+3];
    const float2* p = (const float2*)uB + ((size_t)b * LEN + c * CHUNK) * KHALF + k;
    float s0 = 0.f, s1 = 0.f;
    #pragma unroll 8
    for (int j = 0; j < CHUNK; ++j) {
        const float2 uv = p[(size_t)j * KHALF];
        const float t0 = fmaf(s0, a00, fmaf(s1, a10, uv.x));
        const float t1 = fmaf(s0, a01, fmaf(s1, a11, uv.y));
        s0 = t0; s1 = t1;
    }
    ((float2*)L)[((size_t)b * NCHUNK + c) * KHALF + k] = make_float2(s0, s1);
}

// ---------------- scan phase B: sequential chunk-carry (A^64 by squaring) ----------------
// carry layout: [b][chunk][k] float2 = x_{chunk*64 - 1}
__global__ __launch_bounds__(256)
void scan_carry_kernel(const float* __restrict__ L, const float* __restrict__ A,
                       const float* __restrict__ x0, float* __restrict__ carry)
{
    const int b = blockIdx.x, k = threadIdx.x;
    float m00 = A[4*k+0], m01 = A[4*k+1], m10 = A[4*k+2], m11 = A[4*k+3];
    #pragma unroll
    for (int i = 0; i < 6; ++i) {  // A^64
        const float n00 = m00*m00 + m01*m10;
        const float n01 = m00*m01 + m01*m11;
        const float n10 = m10*m00 + m11*m10;
        const float n11 = m10*m01 + m11*m11;
        m00 = n00; m01 = n01; m10 = n10; m11 = n11;
    }
    float c0 = x0[((size_t)b * KHALF + k) * 2 + 0];
    float c1 = x0[((size_t)b * KHALF + k) * 2 + 1];
    for (int c = 0; c < NCHUNK; ++c) {
        ((float2*)carry)[((size_t)b * NCHUNK + c) * KHALF + k] = make_float2(c0, c1);
        const float2 Lc = ((const float2*)L)[((size_t)b * NCHUNK + c) * KHALF + k];
        const float t0 = c0 * m00 + c1 * m10 + Lc.x;
        const float t1 = c0 * m01 + c1 * m11 + Lc.y;
        c0 = t0; c1 = t1;
    }
}

// ---------------- scan phase C: final pass, writes x as bf16 + new_state f32 ----------------
__global__ __launch_bounds__(256)
void scan_final_kernel(const float* __restrict__ uB, const float* __restrict__ A,
                       const float* __restrict__ carry, ushort* __restrict__ xbf,
                       float* __restrict__ state_out)
{
    const int c = blockIdx.x, b = blockIdx.y, k = threadIdx.x;
    const float a00 = A[4*k+0], a01 = A[4*k+1], a10 = A[4*k+2], a11 = A[4*k+3];
    const float2 s = ((const float2*)carry)[((size_t)b * NCHUNK + c) * KHALF + k];
    float s0 = s.x, s1 = s.y;
    const float2* p = (const float2*)uB + ((size_t)b * LEN + c * CHUNK) * KHALF + k;
    uint* xp = (uint*)xbf + ((size_t)b * LEN + c * CHUNK) * KHALF + k;
    #pragma unroll 8
    for (int j = 0; j < CHUNK; ++j) {
        const float2 uv = p[(size_t)j * KHALF];
        const float t0 = fmaf(s0, a00, fmaf(s1, a10, uv.x));
        const float t1 = fmaf(s0, a01, fmaf(s1, a11, uv.y));
        s0 = t0; s1 = t1;
        xp[(size_t)j * KHALF] = (uint)f2bf(s0) | ((uint)f2bf(s1) << 16);
    }
    if (c == NCHUNK - 1) {
        ((float2*)state_out)[(size_t)b * KHALF + k] = make_float2(s0, s1);
    }
}

extern "C" void kernel_launch(void* const* d_in, const int* in_sizes, int n_in,
                              void* d_out, int out_size, void* d_ws, size_t ws_size,
                              hipStream_t stream)
{
    (void)in_sizes; (void)n_in; (void)out_size; (void)ws_size;
    const float* u  = (const float*)d_in[0];
    const float* x0 = (const float*)d_in[1];
    const float* A  = (const float*)d_in[2];
    const float* B  = (const float*)d_in[3];
    const float* C  = (const float*)d_in[4];
    const float* w  = (const float*)d_in[5];
    float* y_out = (float*)d_out;
    float* state_out = y_out + (size_t)BATCH * LEN * DOUT;

    char* ws = (char*)d_ws;
    ushort* un    = (ushort*)(ws + 0);           // 32768*1024*2  = 64 MB
    ushort* Bt    = (ushort*)(ws + 67108864);    // 512*1024*2    =  1 MB
    ushort* Ct    = (ushort*)(ws + 68157440);    // 1024*512*2    =  1 MB
    float*  uB    = (float*)(ws + 69206016);     // 32768*512*4   = 64 MB
    ushort* xbf   = (ushort*)(ws + 136314880);   // 32768*512*2   = 32 MB
    float*  L     = (float*)(ws + 169869312);    // 8*64*256*8    =  1 MB
    float*  carry = (float*)(ws + 170917888);    // 8*64*256*8    =  1 MB

    transpose_bf16_kernel<<<dim3((DIN * DST + 255) / 256), 256, 0, stream>>>(B, Bt, DIN, DST);
    transpose_bf16_kernel<<<dim3((DST * DOUT + 255) / 256), 256, 0, stream>>>(C, Ct, DST, DOUT);
    rmsnorm_kernel<<<dim3(BATCH * LEN), 256, 0, stream>>>(u, w, un);
    gemm_bt_kernel<<<dim3(BATCH * LEN / BM, DST / BN), 256, 0, stream>>>(un, Bt, uB, BATCH * LEN, DST, DIN);
    scan_local_kernel<<<dim3(NCHUNK, BATCH), 256, 0, stream>>>(uB, A, L);
    scan_carry_kernel<<<dim3(BATCH), 256, 0, stream>>>(L, A, x0, carry);
    scan_final_kernel<<<dim3(NCHUNK, BATCH), 256, 0, stream>>>(uB, A, carry, xbf, state_out);
    gemm_bt_kernel<<<dim3(BATCH * LEN / BM, DOUT / BN), 256, 0, stream>>>(xbf, Ct, y_out, BATCH * LEN, DOUT, DST);
}

// Round 7
// 353.078 us; speedup vs baseline: 1.0701x; 1.0701x over previous
//
#include <hip/hip_runtime.h>
#include <hip/hip_bf16.h>

typedef __attribute__((ext_vector_type(8))) short bf16x8;
typedef __attribute__((ext_vector_type(4))) float f32x4;
typedef __attribute__((ext_vector_type(4))) int int4v;

#define BATCH 8
#define LEN 4096
#define DIN 1024
#define DST 512
#define KHALF 256
#define DOUT 1024
#define NCHUNK 64
#define CHUNK 64

static __device__ __forceinline__ ushort f2bf(float f) {
    uint x = __float_as_uint(f);
    uint r = (x + 0x7fffu + ((x >> 16) & 1u)) >> 16;
    return (ushort)r;
}

// async global->LDS, 16B per lane; LDS dest = wave-uniform base + lane*16
#define GL16(gp, lp) __builtin_amdgcn_global_load_lds( \
    (const __attribute__((address_space(1))) void*)(gp), \
    (__attribute__((address_space(3))) void*)(lp), 16, 0, 0)

// ---------------- rmsnorm: u (32768 x 1024) f32 -> un bf16 ----------------
__global__ __launch_bounds__(256)
void rmsnorm_kernel(const float* __restrict__ u, const float* __restrict__ w,
                    ushort* __restrict__ un)
{
    const int row = blockIdx.x;
    const int t = threadIdx.x;
    const float4 v = ((const float4*)(u + (size_t)row * DIN))[t];
    float ss = v.x*v.x + v.y*v.y + v.z*v.z + v.w*v.w;
    #pragma unroll
    for (int m = 32; m >= 1; m >>= 1) ss += __shfl_xor(ss, m, 64);
    __shared__ float partial[4];
    if ((t & 63) == 0) partial[t >> 6] = ss;
    __syncthreads();
    const float total = partial[0] + partial[1] + partial[2] + partial[3];
    const float scale = rsqrtf(total * (1.0f / DIN) + 1e-6f);
    const float4 wv = ((const float4*)w)[t];
    ushort4 o;
    o.x = f2bf(v.x * scale * wv.x);
    o.y = f2bf(v.y * scale * wv.y);
    o.z = f2bf(v.z * scale * wv.z);
    o.w = f2bf(v.w * scale * wv.w);
    ((ushort4*)(un + (size_t)row * DIN))[t] = o;
}

// ---------------- transpose + cast to bf16 ----------------
__global__ __launch_bounds__(256)
void transpose_bf16_kernel(const float* __restrict__ src, ushort* __restrict__ dst,
                           int R, int C)
{
    const int id = blockIdx.x * 256 + threadIdx.x;
    if (id >= R * C) return;
    const int r = id / C, c = id % C;
    dst[(size_t)c * R + r] = f2bf(src[id]);
}

// ---------------- bf16 MFMA GEMM (m97 structure): A[M][K] @ Bt[N][K] -> C[M][N] f32 ----
// 128x128 tile, BK=64, 4 waves (2x2), global_load_lds staging with pre-swizzled
// source (rule #21: linear LDS dest + inverse-swizzled global src + swizzled read).
// XCD-banded 1D block swizzle: xcd = b&7 owns a band of m-tiles, n fastest.
#define BM 128
#define BN 128
#define BK 64
__global__ __launch_bounds__(256, 3)
void gemm_bt_kernel(const ushort* __restrict__ A, const ushort* __restrict__ Bt,
                    float* __restrict__ C, int M, int N, int K, int Nt)
{
    __shared__ ushort sA[BM * BK];
    __shared__ ushort sB[BN * BK];
    const int tid = threadIdx.x;
    const int lane = tid & 63;
    const int wave = tid >> 6;
    const int wr = wave >> 1, wc = wave & 1;

    const int b = blockIdx.x;
    const int slot = b >> 3;
    const int mt = (b & 7) + 8 * (slot / Nt);
    const int nt = slot - (slot / Nt) * Nt;
    const int m0 = mt * BM, n0 = nt * BN;

    const size_t K2 = (size_t)K * 2;          // bytes per row
    // staging: thread t owns LDS bytes [c*4096 + t*16, +16), i.e. row c*32+(t>>3),
    // col (t&7)*16. Source col is XOR-swizzled so the LDS image is the swizzled layout.
    const int srow = tid >> 3;                // 0..31
    const int scol = ((tid & 7) << 4) ^ ((srow & 7) << 4);
    const char* gA = (const char*)A + (size_t)(m0 + srow) * K2 + scol;
    const char* gB = (const char*)Bt + (size_t)(n0 + srow) * K2 + scol;
    const int ldsBase = wave * 1024;          // + c*4096; HW adds lane*16

    f32x4 acc[4][4] = {};

    const int nkt = K / BK;
    for (int kt = 0; kt < nkt; ++kt) {
        __syncthreads();                      // previous tile's compute done
        const size_t kOff = (size_t)kt * (BK * 2);
        #pragma unroll
        for (int c2 = 0; c2 < 4; ++c2) {
            GL16(gA + (size_t)c2 * 32 * K2 + kOff, (char*)sA + ldsBase + c2 * 4096);
            GL16(gB + (size_t)c2 * 32 * K2 + kOff, (char*)sB + ldsBase + c2 * 4096);
        }
        __syncthreads();                      // compiler drains vmcnt(0) here
        #pragma unroll
        for (int kk = 0; kk < 2; ++kk) {
            bf16x8 af[4], bfr[4];
            #pragma unroll
            for (int i = 0; i < 4; ++i) {
                const int arow = wr * 64 + i * 16 + (lane & 15);
                const int aoff = arow * 128 + ((kk * 64 + (lane >> 4) * 16) ^ ((arow & 7) << 4));
                af[i] = *(const bf16x8*)((const char*)sA + aoff);
                const int brow = wc * 64 + i * 16 + (lane & 15);
                const int boff = brow * 128 + ((kk * 64 + (lane >> 4) * 16) ^ ((brow & 7) << 4));
                bfr[i] = *(const bf16x8*)((const char*)sB + boff);
            }
            #pragma unroll
            for (int i = 0; i < 4; ++i)
                #pragma unroll
                for (int j = 0; j < 4; ++j)
                    acc[i][j] = __builtin_amdgcn_mfma_f32_16x16x32_bf16(af[i], bfr[j], acc[i][j], 0, 0, 0);
        }
    }
    // epilogue: C[(lane>>4)*4 + r][lane&15] per frag (m89-verified layout)
    #pragma unroll
    for (int i = 0; i < 4; ++i) {
        #pragma unroll
        for (int j = 0; j < 4; ++j) {
            const int row = m0 + wr * 64 + i * 16 + (lane >> 4) * 4;
            const int col = n0 + wc * 64 + j * 16 + (lane & 15);
            float* cp = C + (size_t)row * N + col;
            #pragma unroll
            for (int r = 0; r < 4; ++r)
                cp[(size_t)r * N] = acc[i][j][r];
        }
    }
}

// ---------------- scan phase A: per-chunk local finals (zero carry-in) ----------------
__global__ __launch_bounds__(256)
void scan_local_kernel(const float* __restrict__ uB, const float* __restrict__ A,
                       float* __restrict__ L)
{
    const int c = blockIdx.x, b = blockIdx.y, k = threadIdx.x;
    const float a00 = A[4*k+0], a01 = A[4*k+1], a10 = A[4*k+2], a11 = A[4*k+3];
    const float2* p = (const float2*)uB + ((size_t)b * LEN + c * CHUNK) * KHALF + k;
    float s0 = 0.f, s1 = 0.f;
    #pragma unroll 8
    for (int j = 0; j < CHUNK; ++j) {
        const float2 uv = p[(size_t)j * KHALF];
        const float t0 = fmaf(s0, a00, fmaf(s1, a10, uv.x));
        const float t1 = fmaf(s0, a01, fmaf(s1, a11, uv.y));
        s0 = t0; s1 = t1;
    }
    ((float2*)L)[((size_t)b * NCHUNK + c) * KHALF + k] = make_float2(s0, s1);
}

// ---------------- scan phase B: sequential chunk-carry (A^64 by squaring) ----------------
__global__ __launch_bounds__(256)
void scan_carry_kernel(const float* __restrict__ L, const float* __restrict__ A,
                       const float* __restrict__ x0, float* __restrict__ carry)
{
    const int b = blockIdx.x, k = threadIdx.x;
    float m00 = A[4*k+0], m01 = A[4*k+1], m10 = A[4*k+2], m11 = A[4*k+3];
    #pragma unroll
    for (int i = 0; i < 6; ++i) {  // A^64
        const float n00 = m00*m00 + m01*m10;
        const float n01 = m00*m01 + m01*m11;
        const float n10 = m10*m00 + m11*m10;
        const float n11 = m10*m01 + m11*m11;
        m00 = n00; m01 = n01; m10 = n10; m11 = n11;
    }
    float c0 = x0[((size_t)b * KHALF + k) * 2 + 0];
    float c1 = x0[((size_t)b * KHALF + k) * 2 + 1];
    for (int c = 0; c < NCHUNK; ++c) {
        ((float2*)carry)[((size_t)b * NCHUNK + c) * KHALF + k] = make_float2(c0, c1);
        const float2 Lc = ((const float2*)L)[((size_t)b * NCHUNK + c) * KHALF + k];
        const float t0 = c0 * m00 + c1 * m10 + Lc.x;
        const float t1 = c0 * m01 + c1 * m11 + Lc.y;
        c0 = t0; c1 = t1;
    }
}

// ---------------- scan phase C: final pass, writes x as bf16 + new_state f32 ----------------
__global__ __launch_bounds__(256)
void scan_final_kernel(const float* __restrict__ uB, const float* __restrict__ A,
                       const float* __restrict__ carry, ushort* __restrict__ xbf,
                       float* __restrict__ state_out)
{
    const int c = blockIdx.x, b = blockIdx.y, k = threadIdx.x;
    const float a00 = A[4*k+0], a01 = A[4*k+1], a10 = A[4*k+2], a11 = A[4*k+3];
    const float2 s = ((const float2*)carry)[((size_t)b * NCHUNK + c) * KHALF + k];
    float s0 = s.x, s1 = s.y;
    const float2* p = (const float2*)uB + ((size_t)b * LEN + c * CHUNK) * KHALF + k;
    uint* xp = (uint*)xbf + ((size_t)b * LEN + c * CHUNK) * KHALF + k;
    #pragma unroll 8
    for (int j = 0; j < CHUNK; ++j) {
        const float2 uv = p[(size_t)j * KHALF];
        const float t0 = fmaf(s0, a00, fmaf(s1, a10, uv.x));
        const float t1 = fmaf(s0, a01, fmaf(s1, a11, uv.y));
        s0 = t0; s1 = t1;
        xp[(size_t)j * KHALF] = (uint)f2bf(s0) | ((uint)f2bf(s1) << 16);
    }
    if (c == NCHUNK - 1) {
        ((float2*)state_out)[(size_t)b * KHALF + k] = make_float2(s0, s1);
    }
}

extern "C" void kernel_launch(void* const* d_in, const int* in_sizes, int n_in,
                              void* d_out, int out_size, void* d_ws, size_t ws_size,
                              hipStream_t stream)
{
    (void)in_sizes; (void)n_in; (void)out_size; (void)ws_size;
    const float* u  = (const float*)d_in[0];
    const float* x0 = (const float*)d_in[1];
    const float* A  = (const float*)d_in[2];
    const float* B  = (const float*)d_in[3];
    const float* C  = (const float*)d_in[4];
    const float* w  = (const float*)d_in[5];
    float* y_out = (float*)d_out;
    float* state_out = y_out + (size_t)BATCH * LEN * DOUT;

    char* ws = (char*)d_ws;
    ushort* un    = (ushort*)(ws + 0);           // 64 MB
    ushort* Bt    = (ushort*)(ws + 67108864);    //  1 MB
    ushort* Ct    = (ushort*)(ws + 68157440);    //  1 MB
    float*  uB    = (float*)(ws + 69206016);     // 64 MB
    ushort* xbf   = (ushort*)(ws + 136314880);   // 32 MB
    float*  L     = (float*)(ws + 169869312);    //  1 MB
    float*  carry = (float*)(ws + 170917888);    //  1 MB

    transpose_bf16_kernel<<<dim3((DIN * DST + 255) / 256), 256, 0, stream>>>(B, Bt, DIN, DST);
    transpose_bf16_kernel<<<dim3((DST * DOUT + 255) / 256), 256, 0, stream>>>(C, Ct, DST, DOUT);
    rmsnorm_kernel<<<dim3(BATCH * LEN), 256, 0, stream>>>(u, w, un);
    // GEMM1: 32768x512x1024, Mt=256, Nt=4 -> 1024 blocks
    gemm_bt_kernel<<<dim3(256 * 4), 256, 0, stream>>>(un, Bt, uB, BATCH * LEN, DST, DIN, 4);
    scan_local_kernel<<<dim3(NCHUNK, BATCH), 256, 0, stream>>>(uB, A, L);
    scan_carry_kernel<<<dim3(BATCH), 256, 0, stream>>>(L, A, x0, carry);
    scan_final_kernel<<<dim3(NCHUNK, BATCH), 256, 0, stream>>>(uB, A, carry, xbf, state_out);
    // GEMM2: 32768x1024x512, Mt=256, Nt=8 -> 2048 blocks
    gemm_bt_kernel<<<dim3(256 * 8), 256, 0, stream>>>(xbf, Ct, y_out, BATCH * LEN, DOUT, DST, 8);
}

// Round 16
// 340.551 us; speedup vs baseline: 1.1094x; 1.0368x over previous
//
#include <hip/hip_runtime.h>
#include <hip/hip_bf16.h>

typedef __attribute__((ext_vector_type(8))) short bf16x8;
typedef __attribute__((ext_vector_type(4))) float f32x4;
typedef __attribute__((ext_vector_type(4))) int int4v;

#define BATCH 8
#define LEN 4096
#define DIN 1024
#define DST 512
#define KHALF 256
#define DOUT 1024
#define NCHUNK 64
#define CHUNK 64

static __device__ __forceinline__ ushort f2bf(float f) {
    uint x = __float_as_uint(f);
    uint r = (x + 0x7fffu + ((x >> 16) & 1u)) >> 16;
    return (ushort)r;
}
static __device__ __forceinline__ float bf2f(ushort u) {
    return __uint_as_float((uint)u << 16);
}

// async global->LDS, 16B per lane; LDS dest = wave-uniform base + lane*16
#define GL16(gp, lp) __builtin_amdgcn_global_load_lds( \
    (const __attribute__((address_space(1))) void*)(gp), \
    (__attribute__((address_space(3))) void*)(lp), 16, 0, 0)

// ---------------- rmsnorm: u (32768 x 1024) f32 -> un bf16 ----------------
__global__ __launch_bounds__(256)
void rmsnorm_kernel(const float* __restrict__ u, const float* __restrict__ w,
                    ushort* __restrict__ un)
{
    const int row = blockIdx.x;
    const int t = threadIdx.x;
    const float4 v = ((const float4*)(u + (size_t)row * DIN))[t];
    float ss = v.x*v.x + v.y*v.y + v.z*v.z + v.w*v.w;
    #pragma unroll
    for (int m = 32; m >= 1; m >>= 1) ss += __shfl_xor(ss, m, 64);
    __shared__ float partial[4];
    if ((t & 63) == 0) partial[t >> 6] = ss;
    __syncthreads();
    const float total = partial[0] + partial[1] + partial[2] + partial[3];
    const float scale = rsqrtf(total * (1.0f / DIN) + 1e-6f);
    const float4 wv = ((const float4*)w)[t];
    ushort4 o;
    o.x = f2bf(v.x * scale * wv.x);
    o.y = f2bf(v.y * scale * wv.y);
    o.z = f2bf(v.z * scale * wv.z);
    o.w = f2bf(v.w * scale * wv.w);
    ((ushort4*)(un + (size_t)row * DIN))[t] = o;
}

// ---------------- transpose + cast to bf16 ----------------
__global__ __launch_bounds__(256)
void transpose_bf16_kernel(const float* __restrict__ src, ushort* __restrict__ dst,
                           int R, int C)
{
    const int id = blockIdx.x * 256 + threadIdx.x;
    if (id >= R * C) return;
    const int r = id / C, c = id % C;
    dst[(size_t)c * R + r] = f2bf(src[id]);
}

// ---------------- bf16 MFMA GEMM (m97 structure): A[M][K] @ Bt[N][K] -> C[M][N] ----
// 128x128 tile, BK=64, 4 waves (2x2), global_load_lds staging with pre-swizzled
// source (rule #21). XCD-banded 1D block swizzle. Output f32 (obf=0) or bf16 (obf=1).
#define BM 128
#define BN 128
#define BK 64
__global__ __launch_bounds__(256, 3)
void gemm_bt_kernel(const ushort* __restrict__ A, const ushort* __restrict__ Bt,
                    void* __restrict__ Cout, int M, int N, int K, int Nt, int obf)
{
    __shared__ ushort sA[BM * BK];
    __shared__ ushort sB[BN * BK];
    const int tid = threadIdx.x;
    const int lane = tid & 63;
    const int wave = tid >> 6;
    const int wr = wave >> 1, wc = wave & 1;

    const int b = blockIdx.x;
    const int slot = b >> 3;
    const int mt = (b & 7) + 8 * (slot / Nt);
    const int nt = slot - (slot / Nt) * Nt;
    const int m0 = mt * BM, n0 = nt * BN;

    const size_t K2 = (size_t)K * 2;          // bytes per row
    const int srow = tid >> 3;                // 0..31
    const int scol = ((tid & 7) << 4) ^ ((srow & 7) << 4);
    const char* gA = (const char*)A + (size_t)(m0 + srow) * K2 + scol;
    const char* gB = (const char*)Bt + (size_t)(n0 + srow) * K2 + scol;
    const int ldsBase = wave * 1024;          // + c2*4096; HW adds lane*16

    f32x4 acc[4][4] = {};

    const int nkt = K / BK;
    for (int kt = 0; kt < nkt; ++kt) {
        __syncthreads();                      // previous tile's compute done
        const size_t kOff = (size_t)kt * (BK * 2);
        #pragma unroll
        for (int c2 = 0; c2 < 4; ++c2) {
            GL16(gA + (size_t)c2 * 32 * K2 + kOff, (char*)sA + ldsBase + c2 * 4096);
            GL16(gB + (size_t)c2 * 32 * K2 + kOff, (char*)sB + ldsBase + c2 * 4096);
        }
        __syncthreads();                      // compiler drains vmcnt(0) here
        #pragma unroll
        for (int kk = 0; kk < 2; ++kk) {
            bf16x8 af[4], bfr[4];
            #pragma unroll
            for (int i = 0; i < 4; ++i) {
                const int arow = wr * 64 + i * 16 + (lane & 15);
                const int aoff = arow * 128 + ((kk * 64 + (lane >> 4) * 16) ^ ((arow & 7) << 4));
                af[i] = *(const bf16x8*)((const char*)sA + aoff);
                const int brow = wc * 64 + i * 16 + (lane & 15);
                const int boff = brow * 128 + ((kk * 64 + (lane >> 4) * 16) ^ ((brow & 7) << 4));
                bfr[i] = *(const bf16x8*)((const char*)sB + boff);
            }
            #pragma unroll
            for (int i = 0; i < 4; ++i)
                #pragma unroll
                for (int j = 0; j < 4; ++j)
                    acc[i][j] = __builtin_amdgcn_mfma_f32_16x16x32_bf16(af[i], bfr[j], acc[i][j], 0, 0, 0);
        }
    }
    // epilogue: C[(lane>>4)*4 + r][lane&15] per frag (m89-verified layout)
    if (obf) {
        ushort* base = (ushort*)Cout;
        #pragma unroll
        for (int i = 0; i < 4; ++i) {
            #pragma unroll
            for (int j = 0; j < 4; ++j) {
                const int row = m0 + wr * 64 + i * 16 + (lane >> 4) * 4;
                const int col = n0 + wc * 64 + j * 16 + (lane & 15);
                ushort* cp = base + (size_t)row * N + col;
                #pragma unroll
                for (int r = 0; r < 4; ++r)
                    cp[(size_t)r * N] = f2bf(acc[i][j][r]);
            }
        }
    } else {
        float* base = (float*)Cout;
        #pragma unroll
        for (int i = 0; i < 4; ++i) {
            #pragma unroll
            for (int j = 0; j < 4; ++j) {
                const int row = m0 + wr * 64 + i * 16 + (lane >> 4) * 4;
                const int col = n0 + wc * 64 + j * 16 + (lane & 15);
                float* cp = base + (size_t)row * N + col;
                #pragma unroll
                for (int r = 0; r < 4; ++r)
                    cp[(size_t)r * N] = acc[i][j][r];
            }
        }
    }
}

// ---------------- scan phase A: per-chunk local finals (zero carry-in) ----------------
// uB is bf16-packed [b][l][k][2]
__global__ __launch_bounds__(256)
void scan_local_kernel(const ushort* __restrict__ uB, const float* __restrict__ A,
                       float* __restrict__ L)
{
    const int c = blockIdx.x, b = blockIdx.y, k = threadIdx.x;
    const float a00 = A[4*k+0], a01 = A[4*k+1], a10 = A[4*k+2], a11 = A[4*k+3];
    const ushort2* p = (const ushort2*)uB + ((size_t)b * LEN + c * CHUNK) * KHALF + k;
    float s0 = 0.f, s1 = 0.f;
    #pragma unroll 8
    for (int j = 0; j < CHUNK; ++j) {
        const ushort2 uv = p[(size_t)j * KHALF];
        const float ux = bf2f(uv.x), uy = bf2f(uv.y);
        const float t0 = fmaf(s0, a00, fmaf(s1, a10, ux));
        const float t1 = fmaf(s0, a01, fmaf(s1, a11, uy));
        s0 = t0; s1 = t1;
    }
    ((float2*)L)[((size_t)b * NCHUNK + c) * KHALF + k] = make_float2(s0, s1);
}

// ---------------- scan phase B: sequential chunk-carry (A^64 by squaring) ----------------
__global__ __launch_bounds__(256)
void scan_carry_kernel(const float* __restrict__ L, const float* __restrict__ A,
                       const float* __restrict__ x0, float* __restrict__ carry)
{
    const int b = blockIdx.x, k = threadIdx.x;
    float m00 = A[4*k+0], m01 = A[4*k+1], m10 = A[4*k+2], m11 = A[4*k+3];
    #pragma unroll
    for (int i = 0; i < 6; ++i) {  // A^64
        const float n00 = m00*m00 + m01*m10;
        const float n01 = m00*m01 + m01*m11;
        const float n10 = m10*m00 + m11*m10;
        const float n11 = m10*m01 + m11*m11;
        m00 = n00; m01 = n01; m10 = n10; m11 = n11;
    }
    float c0 = x0[((size_t)b * KHALF + k) * 2 + 0];
    float c1 = x0[((size_t)b * KHALF + k) * 2 + 1];
    for (int c = 0; c < NCHUNK; ++c) {
        ((float2*)carry)[((size_t)b * NCHUNK + c) * KHALF + k] = make_float2(c0, c1);
        const float2 Lc = ((const float2*)L)[((size_t)b * NCHUNK + c) * KHALF + k];
        const float t0 = c0 * m00 + c1 * m10 + Lc.x;
        const float t1 = c0 * m01 + c1 * m11 + Lc.y;
        c0 = t0; c1 = t1;
    }
}

// ---------------- scan phase C: final pass, writes x as bf16 + new_state f32 ----------------
__global__ __launch_bounds__(256)
void scan_final_kernel(const ushort* __restrict__ uB, const float* __restrict__ A,
                       const float* __restrict__ carry, ushort* __restrict__ xbf,
                       float* __restrict__ state_out)
{
    const int c = blockIdx.x, b = blockIdx.y, k = threadIdx.x;
    const float a00 = A[4*k+0], a01 = A[4*k+1], a10 = A[4*k+2], a11 = A[4*k+3];
    const float2 s = ((const float2*)carry)[((size_t)b * NCHUNK + c) * KHALF + k];
    float s0 = s.x, s1 = s.y;
    const ushort2* p = (const ushort2*)uB + ((size_t)b * LEN + c * CHUNK) * KHALF + k;
    uint* xp = (uint*)xbf + ((size_t)b * LEN + c * CHUNK) * KHALF + k;
    #pragma unroll 8
    for (int j = 0; j < CHUNK; ++j) {
        const ushort2 uv = p[(size_t)j * KHALF];
        const float ux = bf2f(uv.x), uy = bf2f(uv.y);
        const float t0 = fmaf(s0, a00, fmaf(s1, a10, ux));
        const float t1 = fmaf(s0, a01, fmaf(s1, a11, uy));
        s0 = t0; s1 = t1;
        xp[(size_t)j * KHALF] = (uint)f2bf(s0) | ((uint)f2bf(s1) << 16);
    }
    if (c == NCHUNK - 1) {
        ((float2*)state_out)[(size_t)b * KHALF + k] = make_float2(s0, s1);
    }
}

extern "C" void kernel_launch(void* const* d_in, const int* in_sizes, int n_in,
                              void* d_out, int out_size, void* d_ws, size_t ws_size,
                              hipStream_t stream)
{
    (void)in_sizes; (void)n_in; (void)out_size; (void)ws_size;
    const float* u  = (const float*)d_in[0];
    const float* x0 = (const float*)d_in[1];
    const float* A  = (const float*)d_in[2];
    const float* B  = (const float*)d_in[3];
    const float* C  = (const float*)d_in[4];
    const float* w  = (const float*)d_in[5];
    float* y_out = (float*)d_out;
    float* state_out = y_out + (size_t)BATCH * LEN * DOUT;

    char* ws = (char*)d_ws;
    ushort* un    = (ushort*)(ws + 0);           // 64 MB
    ushort* Bt    = (ushort*)(ws + 67108864);    //  1 MB
    ushort* Ct    = (ushort*)(ws + 68157440);    //  1 MB
    ushort* uBbf  = (ushort*)(ws + 69206016);    // 32 MB (bf16 now)
    ushort* xbf   = (ushort*)(ws + 136314880);   // 32 MB
    float*  L     = (float*)(ws + 169869312);    //  1 MB
    float*  carry = (float*)(ws + 170917888);    //  1 MB

    transpose_bf16_kernel<<<dim3((DIN * DST + 255) / 256), 256, 0, stream>>>(B, Bt, DIN, DST);
    transpose_bf16_kernel<<<dim3((DST * DOUT + 255) / 256), 256, 0, stream>>>(C, Ct, DST, DOUT);
    rmsnorm_kernel<<<dim3(BATCH * LEN), 256, 0, stream>>>(u, w, un);
    // GEMM1: 32768x512x1024, Mt=256, Nt=4 -> 1024 blocks; bf16 output
    gemm_bt_kernel<<<dim3(256 * 4), 256, 0, stream>>>(un, Bt, (void*)uBbf, BATCH * LEN, DST, DIN, 4, 1);
    scan_local_kernel<<<dim3(NCHUNK, BATCH), 256, 0, stream>>>(uBbf, A, L);
    scan_carry_kernel<<<dim3(BATCH), 256, 0, stream>>>(L, A, x0, carry);
    scan_final_kernel<<<dim3(NCHUNK, BATCH), 256, 0, stream>>>(uBbf, A, carry, xbf, state_out);
    // GEMM2: 32768x1024x512, Mt=256, Nt=8 -> 2048 blocks; f32 output
    gemm_bt_kernel<<<dim3(256 * 8), 256, 0, stream>>>(xbf, Ct, (void*)y_out, BATCH * LEN, DOUT, DST, 8, 0);
}